// Round 11
// baseline (90.640 us; speedup 1.0000x reference)
//
#include <hip/hip_runtime.h>
#include <hip/hip_bf16.h>

// ClusterAssignment: q[n,k] = (1/(1+||z_n-c_k||^2)) / sum_k(...)
// N=65536, K=64, D=128, fp32. ALPHA=1.0 -> power = 1.
//
// Round 11: two-kernel split. Round-10 (MFMA) dropped kernel time below the
// 44 us harness fill (absent from top-5) -> ~25-30 us; bench floor ~55 us of
// uncontrollable reset overhead. Remaining kernel cost is the per-block
// serial setup chain (stage->sync->cnorm+atomics+ds_reads->sync) at only
// 2 blocks/CU residency. Fix: prep kernel (1 block) writes bf16 centroids
// (16 KB, L1-resident thereafter) + b_k = 1+||c_k||^2 into d_ws; main
// kernel has NO LDS / NO barriers / NO atomics, B-frags via 16B global
// loads, waves independent. Grid 1024x256 (16 rows/wave) = 4 waves/SIMD;
// rolling B-frag loads keep VGPR ~100.
//
// Numerics unchanged from round 10 (absmax 1.2e-4): dot bf16, znorm/cnorm
// fp32-exact, rcpf for both reciprocals.
//
// MFMA layout (mfma_f32_16x16x32_bf16, m89-verified):
//   A: lane holds z[row=lane&15][k = kk*32 + (lane>>4)*8 + j]
//   B: lane holds c[n  =lane&15+nt*16][same k]
//   C/D: col = lane&15 (+16*nt), row = (lane>>4)*4 + reg

using bf16x8 = __attribute__((ext_vector_type(8))) __bf16;
using f32x4  = __attribute__((ext_vector_type(4))) float;

constexpr int K_CL = 64;
constexpr int D_FT = 128;

// ---- prep: cluster c = t>>2, quarter q = t&3 (256 threads, 1 block)
__global__ __launch_bounds__(256) void prep_kernel(
    const float* __restrict__ cent,
    __bf16* __restrict__ cb,        // [64][128] bf16, packed
    float* __restrict__ bv)         // [64] = 1 + ||c_k||^2
{
    const int t = threadIdx.x;
    const int c = t >> 2, q = t & 3;
    const float4* p = reinterpret_cast<const float4*>(cent + c * D_FT + q * 32);
    bf16x8* dst = reinterpret_cast<bf16x8*>(cb + c * D_FT + q * 32);
    float s = 0.f;
    #pragma unroll
    for (int h = 0; h < 4; ++h) {
        float4 u = p[2 * h], v = p[2 * h + 1];
        s = fmaf(u.x, u.x, s); s = fmaf(u.y, u.y, s);
        s = fmaf(u.z, u.z, s); s = fmaf(u.w, u.w, s);
        s = fmaf(v.x, v.x, s); s = fmaf(v.y, v.y, s);
        s = fmaf(v.z, v.z, s); s = fmaf(v.w, v.w, s);
        bf16x8 a;
        a[0] = (__bf16)u.x; a[1] = (__bf16)u.y;
        a[2] = (__bf16)u.z; a[3] = (__bf16)u.w;
        a[4] = (__bf16)v.x; a[5] = (__bf16)v.y;
        a[6] = (__bf16)v.z; a[7] = (__bf16)v.w;
        dst[h] = a;
    }
    s += __shfl_xor(s, 1);
    s += __shfl_xor(s, 2);
    if (q == 0) bv[c] = 1.f + s;
}

// ---- main: 4 waves/block, wave handles 16 rows x 64 clusters; no LDS.
__global__ __launch_bounds__(256) void cluster_assign_mfma(
    const float* __restrict__ z,
    const __bf16* __restrict__ cb,
    const float* __restrict__ bv,
    float* __restrict__ out)
{
    const int tid  = threadIdx.x;
    const int wave = tid >> 6;
    const int lane = tid & 63;
    const int lo   = lane & 15;
    const int g    = lane >> 4;

    const int rowbase = blockIdx.x * 64 + wave * 16;

    // ---- load this lane's 32 z floats (row lo of the tile)
    const char* zb = reinterpret_cast<const char*>(z)
                   + (size_t)(rowbase + lo) * 512 + g * 32;
    float4 zst[8];
    #pragma unroll
    for (int kk = 0; kk < 4; ++kk) {
        zst[2*kk]   = *reinterpret_cast<const float4*>(zb + kk * 128);
        zst[2*kk+1] = *reinterpret_cast<const float4*>(zb + kk * 128 + 16);
    }

    // ---- b_k for my 4 column groups (L1-hot after first tile)
    float bmine[4];
    #pragma unroll
    for (int nt = 0; nt < 4; ++nt) bmine[nt] = bv[lo + nt * 16];

    // ---- znorm (fp32-exact), reduced across the 4 g-groups
    float zn = 0.f;
    #pragma unroll
    for (int j = 0; j < 8; ++j) {
        float4 v = zst[j];
        zn = fmaf(v.x, v.x, zn); zn = fmaf(v.y, v.y, zn);
        zn = fmaf(v.z, v.z, zn); zn = fmaf(v.w, v.w, zn);
    }
    zn += __shfl_xor(zn, 16);
    zn += __shfl_xor(zn, 32);   // zn = ||z_row(lo)||^2 on all lanes

    // ---- pack A fragments (bf16 RNE)
    bf16x8 af[4];
    #pragma unroll
    for (int kk = 0; kk < 4; ++kk) {
        float4 u = zst[2*kk], v = zst[2*kk+1];
        bf16x8 a;
        a[0] = (__bf16)u.x; a[1] = (__bf16)u.y;
        a[2] = (__bf16)u.z; a[3] = (__bf16)u.w;
        a[4] = (__bf16)v.x; a[5] = (__bf16)v.y;
        a[6] = (__bf16)v.z; a[7] = (__bf16)v.w;
        af[kk] = a;
    }

    // ---- 16 MFMA, B frags loaded rolling from global (L1-hot, 16 KB)
    f32x4 acc[4] = {{0,0,0,0},{0,0,0,0},{0,0,0,0},{0,0,0,0}};
    #pragma unroll
    for (int kk = 0; kk < 4; ++kk)
        #pragma unroll
        for (int nt = 0; nt < 4; ++nt) {
            bf16x8 b = *reinterpret_cast<const bf16x8*>(
                cb + (lo + nt * 16) * D_FT + kk * 32 + g * 8);
            acc[nt] = __builtin_amdgcn_mfma_f32_16x16x32_bf16(
                          af[kk], b, acc[nt], 0, 0, 0);
        }

    // ---- znorm for my 4 C-rows (C row = g*4+r, zn held at lane row)
    float znr[4];
    #pragma unroll
    for (int r = 0; r < 4; ++r) znr[r] = __shfl(zn, g * 4 + r);

    // ---- numerators + row sums (16-lane shfl_xor reduce)
    float num[4][4];
    float psum[4] = {0.f, 0.f, 0.f, 0.f};
    #pragma unroll
    for (int nt = 0; nt < 4; ++nt)
        #pragma unroll
        for (int r = 0; r < 4; ++r) {
            float d1 = fmaf(-2.f, acc[nt][r], znr[r] + bmine[nt]);
            float nv = __builtin_amdgcn_rcpf(d1);   // 1/(1+dist)
            num[nt][r] = nv;
            psum[r] += nv;
        }
    #pragma unroll
    for (int r = 0; r < 4; ++r) {
        psum[r] += __shfl_xor(psum[r], 1);
        psum[r] += __shfl_xor(psum[r], 2);
        psum[r] += __shfl_xor(psum[r], 4);
        psum[r] += __shfl_xor(psum[r], 8);
        psum[r] = __builtin_amdgcn_rcpf(psum[r]);
    }

    // ---- store: row = rowbase + g*4 + r, col = lo + nt*16
    #pragma unroll
    for (int nt = 0; nt < 4; ++nt)
        #pragma unroll
        for (int r = 0; r < 4; ++r)
            out[(size_t)(rowbase + g * 4 + r) * K_CL + lo + nt * 16]
                = num[nt][r] * psum[r];
}

extern "C" void kernel_launch(void* const* d_in, const int* in_sizes, int n_in,
                              void* d_out, int out_size, void* d_ws, size_t ws_size,
                              hipStream_t stream) {
    const float* z    = (const float*)d_in[0];
    const float* cent = (const float*)d_in[1];
    float* out        = (float*)d_out;

    __bf16* cb = (__bf16*)d_ws;                       // 16384 B
    float*  bv = (float*)((char*)d_ws + 16384);       // 256 B

    prep_kernel<<<dim3(1), dim3(256), 0, stream>>>(cent, cb, bv);
    cluster_assign_mfma<<<dim3(65536 / 64), dim3(256), 0, stream>>>(z, cb, bv, out);
}

// Round 12
// 80.591 us; speedup vs baseline: 1.1247x; 1.1247x over previous
//
#include <hip/hip_runtime.h>
#include <hip/hip_bf16.h>

// ClusterAssignment: q[n,k] = (1/(1+||z_n-c_k||^2)) / sum_k(...)
// N=65536, K=64, D=128, fp32. ALPHA=1.0 -> power = 1.
//
// Round 12: revert round-11 split (it cost +11 us: serial 1-block prep +
// dependent-launch bubble). Back to round-10 single kernel, with the setup
// streamlined to ONE global pass / ONE barrier / NO atomics:
//   thread t owns cluster c=t>>2, quarter q=t&3: loads 8 float4 of cent,
//   converts to 4x bf16x8 (ds_write_b128), accumulates cnorm partial,
//   reduces via shfl_xor(1,2), lane q==0 writes b_lds[c]=1+||c||^2.
//   (round 10 paid a second 32KB global pass + 256 LDS atomics + extra
//   barrier dependency per block for this.)
// Main loop identical to round 10 (measured passing, ~15-25 us):
//   4 waves x 16 rows x 64 clusters, 2 tiles/wave, grid 512.
// Numerics: dot bf16 via MFMA, znorm/cnorm fp32-exact, rcpf (absmax 1.2e-4).
//
// MFMA layout (mfma_f32_16x16x32_bf16, m89-verified):
//   A: lane holds z[row=lane&15][k = kk*32 + (lane>>4)*8 + j]
//   B: lane holds c[n  =lane&15+nt*16][same k]
//   C/D: col = lane&15 (+16*nt), row = (lane>>4)*4 + reg

using bf16x8 = __attribute__((ext_vector_type(8))) __bf16;
using f32x4  = __attribute__((ext_vector_type(4))) float;

constexpr int K_CL = 64;
constexpr int D_FT = 128;
constexpr int CSTR = 136;   // padded bf16 row stride (272 B, 16B-aligned)

__global__ __launch_bounds__(256) void cluster_assign_mfma(
    const float* __restrict__ z,
    const float* __restrict__ cent,
    float* __restrict__ out)
{
    __shared__ __bf16 c_bf[K_CL * CSTR];   // 17408 B
    __shared__ float  b_lds[K_CL];         // 1 + ||c_k||^2

    const int tid  = threadIdx.x;
    const int wave = tid >> 6;
    const int lane = tid & 63;
    const int lo   = lane & 15;
    const int g    = lane >> 4;

    // ---- fused setup: one pass over cent; bf16 stage + cnorm, no atomics
    {
        const int c = tid >> 2, q = tid & 3;
        const float4* p =
            reinterpret_cast<const float4*>(cent + c * D_FT + q * 32);
        bf16x8* dst = reinterpret_cast<bf16x8*>(&c_bf[c * CSTR + q * 32]);
        float s = 0.f;
        #pragma unroll
        for (int h = 0; h < 4; ++h) {
            float4 u = p[2 * h], v = p[2 * h + 1];
            s = fmaf(u.x, u.x, s); s = fmaf(u.y, u.y, s);
            s = fmaf(u.z, u.z, s); s = fmaf(u.w, u.w, s);
            s = fmaf(v.x, v.x, s); s = fmaf(v.y, v.y, s);
            s = fmaf(v.z, v.z, s); s = fmaf(v.w, v.w, s);
            bf16x8 a;
            a[0] = (__bf16)u.x; a[1] = (__bf16)u.y;
            a[2] = (__bf16)u.z; a[3] = (__bf16)u.w;
            a[4] = (__bf16)v.x; a[5] = (__bf16)v.y;
            a[6] = (__bf16)v.z; a[7] = (__bf16)v.w;
            dst[h] = a;
        }
        s += __shfl_xor(s, 1);
        s += __shfl_xor(s, 2);      // q-quarters of cluster c summed
        if (q == 0) b_lds[c] = 1.f + s;
    }
    __syncthreads();

    // ---- B fragments (loop-invariant): 16x ds_read_b128; banks
    //      (4n+16kk)%32, n vs n+8 collide 2-way only = free (m136)
    bf16x8 bfr[4][4];
    #pragma unroll
    for (int nt = 0; nt < 4; ++nt)
        #pragma unroll
        for (int kk = 0; kk < 4; ++kk)
            bfr[nt][kk] = *reinterpret_cast<const bf16x8*>(
                &c_bf[(lo + nt * 16) * CSTR + kk * 32 + g * 8]);

    float bmine[4];
    #pragma unroll
    for (int nt = 0; nt < 4; ++nt) bmine[nt] = b_lds[lo + nt * 16];

    for (int it = 0; it < 2; ++it) {
        const int rowbase = blockIdx.x * 128 + it * 64 + wave * 16;

        // ---- load this lane's 32 z floats (row lo, k-chunks per kk)
        const char* zb = reinterpret_cast<const char*>(z)
                       + (size_t)(rowbase + lo) * 512 + g * 32;
        float4 zst[8];
        #pragma unroll
        for (int kk = 0; kk < 4; ++kk) {
            zst[2*kk]   = *reinterpret_cast<const float4*>(zb + kk * 128);
            zst[2*kk+1] = *reinterpret_cast<const float4*>(zb + kk * 128 + 16);
        }

        // ---- znorm (fp32-exact): partial over 32, reduce over g-groups
        float zn = 0.f;
        #pragma unroll
        for (int j = 0; j < 8; ++j) {
            float4 v = zst[j];
            zn = fmaf(v.x, v.x, zn); zn = fmaf(v.y, v.y, zn);
            zn = fmaf(v.z, v.z, zn); zn = fmaf(v.w, v.w, zn);
        }
        zn += __shfl_xor(zn, 16);
        zn += __shfl_xor(zn, 32);   // zn = ||z_row(lo)||^2 on all lanes

        // ---- pack A fragments (bf16 RNE; compiler pairs into cvt_pk)
        bf16x8 af[4];
        #pragma unroll
        for (int kk = 0; kk < 4; ++kk) {
            float4 u = zst[2*kk], v = zst[2*kk+1];
            bf16x8 a;
            a[0] = (__bf16)u.x; a[1] = (__bf16)u.y;
            a[2] = (__bf16)u.z; a[3] = (__bf16)u.w;
            a[4] = (__bf16)v.x; a[5] = (__bf16)v.y;
            a[6] = (__bf16)v.z; a[7] = (__bf16)v.w;
            af[kk] = a;
        }

        // ---- 16 MFMA: 4 N-tiles x 4 K-steps
        f32x4 acc[4] = {{0,0,0,0},{0,0,0,0},{0,0,0,0},{0,0,0,0}};
        #pragma unroll
        for (int kk = 0; kk < 4; ++kk)
            #pragma unroll
            for (int nt = 0; nt < 4; ++nt)
                acc[nt] = __builtin_amdgcn_mfma_f32_16x16x32_bf16(
                              af[kk], bfr[nt][kk], acc[nt], 0, 0, 0);

        // ---- znorm for my 4 C-rows (C row = g*4+r, zn held at lane row)
        float znr[4];
        #pragma unroll
        for (int r = 0; r < 4; ++r) znr[r] = __shfl(zn, g * 4 + r);

        // ---- numerators + row sums (16-lane shfl_xor reduce)
        float num[4][4];
        float psum[4] = {0.f, 0.f, 0.f, 0.f};
        #pragma unroll
        for (int nt = 0; nt < 4; ++nt)
            #pragma unroll
            for (int r = 0; r < 4; ++r) {
                float d1 = fmaf(-2.f, acc[nt][r], znr[r] + bmine[nt]);
                float nv = __builtin_amdgcn_rcpf(d1);   // 1/(1+dist)
                num[nt][r] = nv;
                psum[r] += nv;
            }
        #pragma unroll
        for (int r = 0; r < 4; ++r) {
            psum[r] += __shfl_xor(psum[r], 1);
            psum[r] += __shfl_xor(psum[r], 2);
            psum[r] += __shfl_xor(psum[r], 4);
            psum[r] += __shfl_xor(psum[r], 8);
            psum[r] = __builtin_amdgcn_rcpf(psum[r]);
        }

        // ---- store: row = rowbase + g*4 + r, col = lo + nt*16
        #pragma unroll
        for (int nt = 0; nt < 4; ++nt)
            #pragma unroll
            for (int r = 0; r < 4; ++r)
                out[(size_t)(rowbase + g * 4 + r) * K_CL + lo + nt * 16]
                    = num[nt][r] * psum[r];
    }
}

extern "C" void kernel_launch(void* const* d_in, const int* in_sizes, int n_in,
                              void* d_out, int out_size, void* d_ws, size_t ws_size,
                              hipStream_t stream) {
    const float* z    = (const float*)d_in[0];
    const float* cent = (const float*)d_in[1];
    float* out        = (float*)d_out;

    dim3 grid(65536 / 128);   // 512 blocks; 128 rows/block (4 waves x 16 x 2)
    cluster_assign_mfma<<<grid, dim3(256), 0, stream>>>(z, cent, out);
}